// Round 1
// baseline (1224.556 us; speedup 1.0000x reference)
//
#include <hip/hip_runtime.h>
#include <hip/hip_bf16.h>
#include <cstdint>
#include <math.h>

#define BM 128
#define BN 128
#define BK 64

typedef __attribute__((ext_vector_type(4))) float f32x4;
typedef __attribute__((ext_vector_type(8))) __bf16 bf16x8;

__device__ __forceinline__ unsigned short f2bf(float f) {
    union { float f; unsigned u; } v; v.f = f;
    unsigned u = v.u + 0x7fffu + ((v.u >> 16) & 1u);
    return (unsigned short)(u >> 16);
}

__device__ __forceinline__ float gelu_tanh(float x) {
    float x3 = x * x * x;
    float t = tanhf(0.7978845608028654f * (x + 0.044715f * x3));
    return 0.5f * x * (1.0f + t);
}

// async global->LDS, 16B per lane. LDS dest is wave-uniform base + lane*16
// (hardware readfirstlanes the pointer); we pass the lane-linear address so
// the wave base is lane 0's address.
__device__ __forceinline__ void gload_lds16(const void* g, void* l) {
    __builtin_amdgcn_global_load_lds(
        (__attribute__((address_space(1))) void*)(uintptr_t)g,
        (__attribute__((address_space(3))) void*)(unsigned)(uintptr_t)l,
        16, 0, 0);
}

// ---------------- fused bias-add + residual + LayerNorm ----------------
// one block per token row; H assumed divisible by 1024 (H=4096 here)
__global__ __launch_bounds__(256)
void fused_add_ln(const float* __restrict__ in, const float* __restrict__ res,
                  const float* __restrict__ bias, const float* __restrict__ nw,
                  const float* __restrict__ nb, float* __restrict__ resadd,
                  unsigned short* __restrict__ lnout, int H) {
    const int row = blockIdx.x;
    const int tid = threadIdx.x;
    const size_t base = (size_t)row * H;
    float v[16];
    float s = 0.f, ss = 0.f;
#pragma unroll
    for (int i = 0; i < 4; ++i) {
        int idx = (i * 256 + tid) * 4;
        float4 a = *(const float4*)(in + base + idx);
        float4 b = *(const float4*)(res + base + idx);
        float4 c = *(const float4*)(bias + idx);
        float x0 = a.x + b.x + c.x, x1 = a.y + b.y + c.y;
        float x2 = a.z + b.z + c.z, x3 = a.w + b.w + c.w;
        v[i * 4 + 0] = x0; v[i * 4 + 1] = x1; v[i * 4 + 2] = x2; v[i * 4 + 3] = x3;
        s += x0 + x1 + x2 + x3;
        ss += x0 * x0 + x1 * x1 + x2 * x2 + x3 * x3;
    }
#pragma unroll
    for (int off = 32; off > 0; off >>= 1) {
        s += __shfl_down(s, off);
        ss += __shfl_down(ss, off);
    }
    __shared__ float red[8];
    const int w = tid >> 6;
    if ((tid & 63) == 0) { red[w] = s; red[4 + w] = ss; }
    __syncthreads();
    s = red[0] + red[1] + red[2] + red[3];
    ss = red[4] + red[5] + red[6] + red[7];
    const float mean = s / H;
    const float var = ss / H - mean * mean;
    const float rstd = rsqrtf(var + 1e-12f);
#pragma unroll
    for (int i = 0; i < 4; ++i) {
        int idx = (i * 256 + tid) * 4;
        float4 wv = *(const float4*)(nw + idx);
        float4 bv = *(const float4*)(nb + idx);
        float4 r;
        r.x = v[i * 4 + 0]; r.y = v[i * 4 + 1]; r.z = v[i * 4 + 2]; r.w = v[i * 4 + 3];
        *(float4*)(resadd + base + idx) = r;
        ushort4 o;
        o.x = f2bf((r.x - mean) * rstd * wv.x + bv.x);
        o.y = f2bf((r.y - mean) * rstd * wv.y + bv.y);
        o.z = f2bf((r.z - mean) * rstd * wv.z + bv.z);
        o.w = f2bf((r.w - mean) * rstd * wv.w + bv.w);
        *(ushort4*)(lnout + base + idx) = o;
    }
}

// ---------------- fp32 -> bf16 weight cast ----------------
__global__ __launch_bounds__(256)
void cast_w(const float* __restrict__ w, unsigned short* __restrict__ o, long long n4) {
    long long i = (long long)blockIdx.x * 256 + threadIdx.x;
    if (i >= n4) return;
    float4 f = *(const float4*)(w + i * 4);
    ushort4 u;
    u.x = f2bf(f.x); u.y = f2bf(f.y); u.z = f2bf(f.z); u.w = f2bf(f.w);
    *(ushort4*)(o + i * 4) = u;
}

// ---------------- bf16 GEMM, C = A * B^T ----------------
// A [M,K] bf16 row-major, B [N,K] bf16 row-major. m97 structure:
// 128x128 tile, BK=64, 4 waves (2x2), global_load_lds(16B) staging,
// XOR swizzle (row&7)<<4 on the LDS byte address applied via pre-swizzled
// global source (global_load_lds writes linearly).
// EPI==0: C_bf16[m,n] = bf16(gelu(acc + bias_n[n]))
// EPI==1: C_f32 [m,n] = acc + bias_n[n] + resadd[m,n]
template <int EPI>
__global__ __launch_bounds__(256, 2)
void gemm_bt(const unsigned short* __restrict__ A,
             const unsigned short* __restrict__ B,
             const float* __restrict__ bias_n,
             const float* __restrict__ resadd,
             void* __restrict__ Cout,
             int M, int N, int K) {
    __shared__ unsigned short sA[BM * BK];
    __shared__ unsigned short sB[BN * BK];
    const int tid = threadIdx.x;
    const int lane = tid & 63;
    const int w = tid >> 6;
    const int wr = w >> 1;
    const int wc = w & 1;
    const int nbx = N / BN;
    const int brow = blockIdx.x / nbx;
    const int bcol = blockIdx.x % nbx;

    f32x4 acc[4][4] = {};

    // staging source coords: linear LDS byte offset o = i*4096 + tid*16,
    // physical (row, physc); the logical column there is physc ^ ((row&7)<<4)
    const int o_lin = tid * 16;
    int st_row[4], st_col[4];
#pragma unroll
    for (int i = 0; i < 4; ++i) {
        int o = i * 4096 + o_lin;
        int r = o >> 7;
        int c = (o & 127) ^ ((r & 7) << 4);
        st_row[i] = r;
        st_col[i] = c >> 1;  // bf16 element offset within the K-slice
    }
    const unsigned short* Ag = A + (size_t)(brow * BM) * K;
    const unsigned short* Bg = B + (size_t)(bcol * BN) * K;

    for (int kt = 0; kt < K; kt += BK) {
#pragma unroll
        for (int i = 0; i < 4; ++i)
            gload_lds16(Ag + (size_t)st_row[i] * K + kt + st_col[i],
                        (char*)sA + i * 4096 + o_lin);
#pragma unroll
        for (int i = 0; i < 4; ++i)
            gload_lds16(Bg + (size_t)st_row[i] * K + kt + st_col[i],
                        (char*)sB + i * 4096 + o_lin);
        __syncthreads();  // compiler emits vmcnt(0) drain before s_barrier

#pragma unroll
        for (int kk = 0; kk < 2; ++kk) {
            bf16x8 af[4], bfr[4];
#pragma unroll
            for (int mi = 0; mi < 4; ++mi) {
                int r = wr * 64 + mi * 16 + (lane & 15);
                int cb = (kk * 64 + (lane >> 4) * 16) ^ ((r & 7) << 4);
                af[mi] = *(const bf16x8*)((const char*)sA + r * 128 + cb);
            }
#pragma unroll
            for (int ni = 0; ni < 4; ++ni) {
                int r = wc * 64 + ni * 16 + (lane & 15);
                int cb = (kk * 64 + (lane >> 4) * 16) ^ ((r & 7) << 4);
                bfr[ni] = *(const bf16x8*)((const char*)sB + r * 128 + cb);
            }
#pragma unroll
            for (int mi = 0; mi < 4; ++mi)
#pragma unroll
                for (int ni = 0; ni < 4; ++ni)
                    acc[mi][ni] = __builtin_amdgcn_mfma_f32_16x16x32_bf16(
                        af[mi], bfr[ni], acc[mi][ni], 0, 0, 0);
        }
        __syncthreads();
    }

    // epilogue: C/D layout col = lane&15, row = (lane>>4)*4 + j
    const int c0 = bcol * BN + wc * 64 + (lane & 15);
    const int r0 = brow * BM + wr * 64 + (lane >> 4) * 4;
#pragma unroll
    for (int mi = 0; mi < 4; ++mi) {
#pragma unroll
        for (int j = 0; j < 4; ++j) {
            const int row = r0 + mi * 16 + j;
#pragma unroll
            for (int ni = 0; ni < 4; ++ni) {
                const int col = c0 + ni * 16;
                float x = acc[mi][ni][j] + bias_n[col];
                if (EPI == 0) {
                    ((unsigned short*)Cout)[(size_t)row * N + col] = f2bf(gelu_tanh(x));
                } else {
                    const size_t off = (size_t)row * N + col;
                    ((float*)Cout)[off] = x + resadd[off];
                }
            }
        }
    }
}

extern "C" void kernel_launch(void* const* d_in, const int* in_sizes, int n_in,
                              void* d_out, int out_size, void* d_ws, size_t ws_size,
                              hipStream_t stream) {
    const float* input    = (const float*)d_in[0];
    const float* residual = (const float*)d_in[1];
    const float* bias     = (const float*)d_in[2];
    const float* attn_nw  = (const float*)d_in[3];
    const float* attn_nb  = (const float*)d_in[4];
    const float* inter_w  = (const float*)d_in[5];
    const float* inter_b  = (const float*)d_in[6];
    const float* output_w = (const float*)d_in[7];
    const float* output_b = (const float*)d_in[8];

    const int H = in_sizes[3];            // 4096
    const int I = in_sizes[6];            // 16384
    const int T = in_sizes[0] / H;        // B*S = 4096

    // workspace layout (bytes):
    // resadd fp32 [T,H] | ln bf16 [T,H] | w1 bf16 [I,H] | w2 bf16 [H,I] | act bf16 [T,I]
    char* ws = (char*)d_ws;
    float* resadd      = (float*)ws;
    unsigned short* ln = (unsigned short*)(ws + (size_t)T * H * 4);
    unsigned short* w1 = (unsigned short*)((char*)ln + (size_t)T * H * 2);
    unsigned short* w2 = w1 + (size_t)I * H;
    unsigned short* act = w2 + (size_t)H * I;

    // 1) fused add + LN
    fused_add_ln<<<T, 256, 0, stream>>>(input, residual, bias, attn_nw, attn_nb,
                                        resadd, ln, H);

    // 2) weight casts fp32 -> bf16 (redone every call; deterministic)
    {
        long long n4 = (long long)I * H / 4;
        int blocks = (int)((n4 + 255) / 256);
        cast_w<<<blocks, 256, 0, stream>>>(inter_w, w1, n4);
        cast_w<<<blocks, 256, 0, stream>>>(output_w, w2, n4);
    }

    // 3) GEMM1: act = gelu(ln @ inter_w^T + inter_b)   [T,I]
    {
        dim3 grid((T / BM) * (I / BN));
        gemm_bt<0><<<grid, 256, 0, stream>>>(ln, w1, inter_b, nullptr, act, T, I, H);
    }

    // 4) GEMM2: out = act @ output_w^T + output_b + resadd   [T,H]
    {
        dim3 grid((T / BM) * (H / BN));
        gemm_bt<1><<<grid, 256, 0, stream>>>(act, w2, output_b, resadd, d_out, T, H, I);
    }
}